// Round 11
// baseline (8262.621 us; speedup 1.0000x reference)
//
#include <hip/hip_runtime.h>
#include <hip/hip_bf16.h>

#define N_PTS 65536
#define MCLUS 4096
#define KNN   16
#define C_IN  128
#define C_OUT 256

typedef unsigned long long u64;
typedef unsigned u32;

// ---------------- workspace layout (bytes) ----------------
#define WS_ID     0
#define WS_SLOTS  16384
#define WS_BBOX   49152
#define WS_CNT    49216
#define WS_OFS    180288
#define WS_NBR    49216
#define WS_POS4   311360
#define WS_PSUM   311360
#define WS_PSUMSQ 835648
#define WS_SCALE  1359936
#define WS_SHIFT  1360960

// order-preserving float<->u32
__device__ __forceinline__ u32 fkey(float v) {
    u32 u = __float_as_uint(v);
    return (u >> 31) ? ~u : (u | 0x80000000u);
}
__device__ __forceinline__ float funkey(u32 k) {
    u32 u = (k >> 31) ? (k & 0x7FFFFFFFu) : ~k;
    return __uint_as_float(u);
}

// ---------------- init: mailbox, id[0], bbox, cell counts ----------------
__global__ void init_kernel(int* __restrict__ id, u64* __restrict__ slots,
                            u32* __restrict__ bbox, int* __restrict__ cellcnt) {
    int t = threadIdx.x;
    for (int i = t; i < 4096; i += 1024) slots[i] = 0ull;   // tag 0 never used
    for (int i = t; i < 32768; i += 1024) cellcnt[i] = 0;
    if (t < 3)   bbox[t] = 0xFFFFFFFFu;       // mins
    if (t >= 3 && t < 6) bbox[t] = 0u;        // maxes
    if (t == 0) id[0] = 0;
}

// ---------------- bbox: wave-reduced atomic min/max ----------------
__global__ __launch_bounds__(256) void bbox_kernel(const float* __restrict__ pos,
                                                   u32* __restrict__ bbox) {
    int t = blockIdx.x * 256 + threadIdx.x;
    u32 mn0 = 0xFFFFFFFFu, mn1 = 0xFFFFFFFFu, mn2 = 0xFFFFFFFFu;
    u32 mx0 = 0u, mx1 = 0u, mx2 = 0u;
    for (int i = t; i < N_PTS; i += 16384) {
        u32 k0 = fkey(pos[i*3+0]), k1 = fkey(pos[i*3+1]), k2 = fkey(pos[i*3+2]);
        mn0 = min(mn0, k0); mn1 = min(mn1, k1); mn2 = min(mn2, k2);
        mx0 = max(mx0, k0); mx1 = max(mx1, k1); mx2 = max(mx2, k2);
    }
    #pragma unroll
    for (int off = 32; off > 0; off >>= 1) {
        mn0 = min(mn0, (u32)__shfl_xor(mn0, off)); mx0 = max(mx0, (u32)__shfl_xor(mx0, off));
        mn1 = min(mn1, (u32)__shfl_xor(mn1, off)); mx1 = max(mx1, (u32)__shfl_xor(mx1, off));
        mn2 = min(mn2, (u32)__shfl_xor(mn2, off)); mx2 = max(mx2, (u32)__shfl_xor(mx2, off));
    }
    if ((threadIdx.x & 63) == 0) {
        atomicMin(&bbox[0], mn0); atomicMin(&bbox[1], mn1); atomicMin(&bbox[2], mn2);
        atomicMax(&bbox[3], mx0); atomicMax(&bbox[4], mx1); atomicMax(&bbox[5], mx2);
    }
}

// 32x32x32 Morton cell (15-bit), 5 bits per axis interleaved
__device__ __forceinline__ int cell_of(float x, float y, float z, const u32* bb) {
    float x0 = funkey(bb[0]), y0 = funkey(bb[1]), z0 = funkey(bb[2]);
    float x1 = funkey(bb[3]), y1 = funkey(bb[4]), z1 = funkey(bb[5]);
    float sx = 32.0f / fmaxf(x1 - x0, 1e-20f);
    float sy = 32.0f / fmaxf(y1 - y0, 1e-20f);
    float sz = 32.0f / fmaxf(z1 - z0, 1e-20f);
    int gx = min(max((int)((x - x0) * sx), 0), 31);
    int gy = min(max((int)((y - y0) * sy), 0), 31);
    int gz = min(max((int)((z - z0) * sz), 0), 31);
    int m = 0;
    #pragma unroll
    for (int k = 0; k < 5; ++k)
        m |= (((gx >> k) & 1) << (3*k + 2)) | (((gy >> k) & 1) << (3*k + 1)) | (((gz >> k) & 1) << (3*k));
    return m;
}

__global__ __launch_bounds__(256) void count_kernel(const float* __restrict__ pos,
                                                    const u32* __restrict__ bbox,
                                                    int* __restrict__ cellcnt) {
    int i = blockIdx.x * 256 + threadIdx.x;
    atomicAdd(&cellcnt[cell_of(pos[i*3+0], pos[i*3+1], pos[i*3+2], bbox)], 1);
}

// exclusive scan of 32768 cell counts: 1024 threads x 32 cells each
__global__ __launch_bounds__(1024) void scan_kernel(const int* __restrict__ cellcnt,
                                                    int* __restrict__ cellofs) {
    __shared__ int ts[1024];
    int t = threadIdx.x;
    int v[32]; int s = 0;
    #pragma unroll
    for (int i = 0; i < 32; ++i) { v[i] = cellcnt[t*32 + i]; s += v[i]; }
    ts[t] = s; __syncthreads();
    for (int off = 1; off < 1024; off <<= 1) {
        int u = (t >= off) ? ts[t - off] : 0;
        __syncthreads();
        ts[t] += u;
        __syncthreads();
    }
    int pre = (t == 0) ? 0 : ts[t - 1];
    #pragma unroll
    for (int i = 0; i < 32; ++i) { cellofs[t*32 + i] = pre; pre += v[i]; }
}

__global__ __launch_bounds__(256) void scatter_kernel(const float* __restrict__ pos,
                                                      const u32* __restrict__ bbox,
                                                      int* __restrict__ cellofs,
                                                      float4* __restrict__ pos4) {
    int i = blockIdx.x * 256 + threadIdx.x;
    float x = pos[i*3+0], y = pos[i*3+1], z = pos[i*3+2];
    int o = atomicAdd(&cellofs[cell_of(x, y, z, bbox)], 1);
    pos4[o] = make_float4(x, y, z, __int_as_float(i));
}

// exact reference arithmetic: ((dx*dx + dy*dy) + dz*dz), no FMA
__device__ __forceinline__ float dist3(float ax, float ay, float az,
                                       float bx, float by, float bz) {
    float dx = __fsub_rn(ax, bx), dy = __fsub_rn(ay, by), dz = __fsub_rn(az, bz);
    return __fadd_rn(__fadd_rn(__fmul_rn(dx, dx), __fmul_rn(dy, dy)), __fmul_rn(dz, dz));
}

__device__ __forceinline__ u32 wave_max_u32(u32 v) {
    #pragma unroll
    for (int off = 32; off > 0; off >>= 1) {
        u32 o = __shfl_xor(v, off);
        v = o > v ? o : v;
    }
    return v;
}
__device__ __forceinline__ u32 wave_min_u32(u32 v) {
    #pragma unroll
    for (int off = 32; off > 0; off >>= 1) {
        u32 o = __shfl_xor(v, off);
        v = o < v ? o : v;
    }
    return v;
}

// argmax over 48-bit keys (md32<<16 | inv16); returns winning lane.
__device__ __forceinline__ int wave_argmax48(u64 k48) {
    u32 hi = (u32)(k48 >> 16);
    u32 him = wave_max_u32(hi);
    u64 ball = __ballot(hi == him);
    if (__popcll(ball) > 1) {
        u32 a = (hi == him) ? (u32)(k48 & 0xFFFFull) : 0u;
        u32 am = wave_max_u32(a);
        ball = __ballot((hi == him) && (a == am));
    }
    return __ffsll((long long)ball) - 1;
}

// ---------------- FPS: optimistic batches + single-slow-round punch-through ----
// 64 blocks x 1 wave, Morton-ordered ownership, 25-word mailbox, 8-candidate sim.
// On violation (j* = global first-bad substep): rollback snapshot, re-apply the
// verified prefix 0..j*-1, then ONE exact 4-word slow round resolves substep j*
// (all blocks are at an identical exact state), then resume batching PAST the
// contested step. Removes r10's repeated-contested-retry and r8's ~5 slow
// rounds per violation. Every violation guarantees j*+1 steps of progress.
__global__ __launch_bounds__(64) void fps_kernel(const float* __restrict__ pos,
                                                 const float4* __restrict__ pos4,
                                                 int* __restrict__ id,
                                                 u64* __restrict__ slots) {
    const int lane = threadIdx.x;
    const int blk  = blockIdx.x;
    __shared__ float bku[1024];                      // md snapshot for rollback

    float px[16], py[16], pz[16], md[16];
    u32 inv[16];
    const float c0x = pos[0], c0y = pos[1], c0z = pos[2];
    #pragma unroll
    for (int e = 0; e < 16; ++e) {
        int sp = blk * 1024 + (lane >> 3) * 128 + e * 8 + (lane & 7);
        float4 v = pos4[sp];
        px[e] = v.x; py[e] = v.y; pz[e] = v.z;
        inv[e] = 0xFFFFu - (u32)__float_as_int(v.w);
        md[e] = dist3(px[e], py[e], pz[e], c0x, c0y, c0z);
    }

    int r = 0;              // mailbox round counter (tag = r+1)
    u32 fb_mine = 0xFu;     // first violated substep of pending sim (0xF = clean/none)
    int s_conf = 0;         // last confirmed id index (id[0] fixed)
    int nsub = 0;           // substeps in pending (tentative) sim
    u64 wk48[8]; float wxa[8], wya[8], wza[8];       // pending winners

    // exact single-step protocol (4-word mailbox): resolves one step from an
    // exact, globally-identical state. Used to punch through contested substeps.
    auto slow_round = [&](int rr, int s) {
        u64 bk = 0; float bx = 0.f, by = 0.f, bz = 0.f;
        #pragma unroll
        for (int e = 0; e < 16; ++e) {
            u64 k = ((u64)__float_as_uint(md[e]) << 16) | inv[e];
            bool bt = k > bk;
            bk = bt ? k : bk; bx = bt ? px[e] : bx; by = bt ? py[e] : by; bz = bt ? pz[e] : bz;
        }
        int src = wave_argmax48(bk);
        float wx = __shfl(bx, src), wy = __shfl(by, src), wz = __shfl(bz, src);
        u64 kb = __shfl(bk, src);

        const u64 tg = (u64)((rr + 1) & 0xFFFF);
        u64* base = &slots[(u32)(rr & 1) * 2048];
        {
            u64 w0 = (kb << 16) | tg;
            u64 w1 = ((u64)__float_as_uint(wx) << 32) | tg;
            u64 w2 = ((u64)__float_as_uint(wy) << 32) | tg;
            u64 w3 = ((u64)__float_as_uint(wz) << 32) | tg;
            u64 wv = (lane == 0) ? w0 : (lane == 1) ? w1 : (lane == 2) ? w2 : w3;
            if (lane < 4)
                __hip_atomic_store(&base[(u32)blk * 32 + (u32)lane], wv,
                                   __ATOMIC_RELAXED, __HIP_MEMORY_SCOPE_AGENT);
        }
        u64* bp = &base[(u32)lane * 32];
        u64 v0, v1, v2, v3;
        for (;;) {
            v0 = __hip_atomic_load(&bp[0], __ATOMIC_RELAXED, __HIP_MEMORY_SCOPE_AGENT);
            v1 = __hip_atomic_load(&bp[1], __ATOMIC_RELAXED, __HIP_MEMORY_SCOPE_AGENT);
            v2 = __hip_atomic_load(&bp[2], __ATOMIC_RELAXED, __HIP_MEMORY_SCOPE_AGENT);
            v3 = __hip_atomic_load(&bp[3], __ATOMIC_RELAXED, __HIP_MEMORY_SCOPE_AGENT);
            u64 bad = ((v0 ^ tg) | (v1 ^ tg) | (v2 ^ tg) | (v3 ^ tg)) & 0xFFFFull;
            if (bad == 0ull) break;
        }
        u64 k2 = v0 >> 16;
        int s2 = wave_argmax48(k2);
        u64 kw = __shfl(k2, s2);
        float cx = __shfl(__uint_as_float((u32)(v1 >> 32)), s2);
        float cy = __shfl(__uint_as_float((u32)(v2 >> 32)), s2);
        float cz = __shfl(__uint_as_float((u32)(v3 >> 32)), s2);
        if (blk == 0 && lane == 0) id[s] = (int)(0xFFFFu - (u32)(kw & 0xFFFFull));
        #pragma unroll
        for (int e = 0; e < 16; ++e)
            md[e] = fminf(md[e], dist3(px[e], py[e], pz[e], cx, cy, cz));
    };

    for (;;) {
        // ---- extract 8 candidates: top-1 of each 8-lane segment (tentative md) ----
        u64 bk = 0; float bx = 0.f, by = 0.f, bz = 0.f;
        #pragma unroll
        for (int e = 0; e < 16; ++e) {
            u64 k = ((u64)__float_as_uint(md[e]) << 16) | inv[e];
            bool bt = k > bk;
            bk = bt ? k : bk; bx = bt ? px[e] : bx; by = bt ? py[e] : by; bz = bt ? pz[e] : bz;
        }
        u64 ks = bk;
        #pragma unroll
        for (int off = 1; off <= 4; off <<= 1) {
            u64 o = __shfl_xor(ks, off);
            if (o > ks) ks = o;
        }
        {   // gather segment-winner position (key unique: contains idx)
            u64 ball = __ballot(bk == ks);
            int segbase = (lane >> 3) << 3;
            int ssrc = __ffsll((long long)(ball & (0xFFull << segbase))) - 1;
            bx = __shfl(bx, ssrc); by = __shfl(by, ssrc); bz = __shfl(bz, ssrc);
        }

        // ---- publish 25 self-tagged words (24 = 8 cands x 3, 1 flag=firstbad) ----
        const u64 tg = (u64)((r + 1) & 0xFFFF);
        u64* base = &slots[(u32)(r & 1) * 2048];
        {
            int c = lane / 3; if (c > 7) c = 7;
            int p = lane - c * 3;
            int srcl = 8 * c;
            u64 kk  = __shfl(ks, srcl);
            float gx = __shfl(bx, srcl), gy = __shfl(by, srcl), gz = __shfl(bz, srcl);
            u32 hi, mid;
            if (p == 0)      { hi = __float_as_uint(gx); mid = (u32)(kk & 0xFFFFull); }
            else if (p == 1) { hi = __float_as_uint(gy); mid = (u32)(kk >> 32) & 0xFFFFu; }
            else             { hi = __float_as_uint(gz); mid = (u32)(kk >> 16) & 0xFFFFu; }
            u64 wd = ((u64)hi << 32) | ((u64)mid << 16) | tg;
            if (lane == 24) wd = ((u64)(fb_mine & 0xFu) << 16) | tg;
            if (lane < 25)
                __hip_atomic_store(&base[(u32)blk * 32 + (u32)lane], wd,
                                   __ATOMIC_RELAXED, __HIP_MEMORY_SCOPE_AGENT);
        }

        // ---- poll: lane l waits for block l's 25 words (reload only stale) ----
        u64 w[25]; u32 valid = 0;
        {
            u64* bp = &base[(u32)lane * 32];
            do {
                #pragma unroll
                for (int i = 0; i < 25; ++i)
                    if (!(valid & (1u << i)))
                        w[i] = __hip_atomic_load(&bp[i], __ATOMIC_RELAXED, __HIP_MEMORY_SCOPE_AGENT);
                #pragma unroll
                for (int i = 0; i < 25; ++i)
                    if ((u32)(w[i] & 0xFFFFull) == (u32)tg) valid |= (1u << i);
            } while (valid != 0x1FFFFFFu);
        }
        ++r;

        // ---- commit decision ----
        u32 jstar = wave_min_u32((u32)(w[24] >> 16) & 0xFu);
        int adv = (jstar < (u32)nsub) ? (int)jstar : nsub;
        if (adv < nsub) {
            // violation: rollback, re-apply verified prefix 0..adv-1 (exact state),
            // then ONE slow round punches through the contested substep.
            #pragma unroll
            for (int e = 0; e < 16; ++e) md[e] = bku[e * 64 + lane];
            #pragma unroll
            for (int j = 0; j < 8; ++j) {
                if (j < adv) {
                    #pragma unroll
                    for (int e = 0; e < 16; ++e)
                        md[e] = fminf(md[e], dist3(px[e], py[e], pz[e], wxa[j], wya[j], wza[j]));
                }
            }
            s_conf += adv; nsub = 0; fb_mine = 0xFu;
            if (s_conf < 4095) {
                slow_round(r, s_conf + 1);   // exact fix of the contested step
                ++r;
                s_conf += 1;
            }
            if (s_conf >= 4095) break;
            continue;    // polled candidates came from corrupted tentative states; discard
        }
        // clean: commit pending sim
        s_conf += nsub; nsub = 0; fb_mine = 0xFu;
        if (s_conf >= 4095) break;
        nsub = (4095 - s_conf) < 8 ? (4095 - s_conf) : 8;

        // ---- parse candidates (lane l holds block l's 8) ----
        float cpx[8], cpy[8], cpz[8], cmdf[8]; u32 cinv[8];
        #pragma unroll
        for (int c = 0; c < 8; ++c) {
            u64 a = w[3 * c], b = w[3 * c + 1], d = w[3 * c + 2];
            cpx[c] = __uint_as_float((u32)(a >> 32));
            cpy[c] = __uint_as_float((u32)(b >> 32));
            cpz[c] = __uint_as_float((u32)(d >> 32));
            cinv[c] = (u32)(a >> 16) & 0xFFFFu;
            u32 mdb = (((u32)(b >> 16) & 0xFFFFu) << 16) | ((u32)(d >> 16) & 0xFFFFu);
            cmdf[c] = __uint_as_float(mdb);
        }

        // ---- snapshot, then simulate nsub substeps over the 512-candidate union ----
        #pragma unroll
        for (int e = 0; e < 16; ++e) bku[e * 64 + lane] = md[e];

        float pwx = 0.f, pwy = 0.f, pwz = 0.f;
        #pragma unroll
        for (int j = 0; j < 8; ++j) {
            if (j < nsub) {
                if (j) {
                    #pragma unroll
                    for (int c = 0; c < 8; ++c)
                        cmdf[c] = fminf(cmdf[c], dist3(cpx[c], cpy[c], cpz[c], pwx, pwy, pwz));
                }
                u64 bk2 = 0; float b2x = 0.f, b2y = 0.f, b2z = 0.f;
                #pragma unroll
                for (int c = 0; c < 8; ++c) {
                    u64 k = ((u64)__float_as_uint(cmdf[c]) << 16) | cinv[c];
                    bool bt = k > bk2;
                    bk2 = bt ? k : bk2; b2x = bt ? cpx[c] : b2x; b2y = bt ? cpy[c] : b2y; b2z = bt ? cpz[c] : b2z;
                }
                int src = wave_argmax48(bk2);
                u64 kw = __shfl(bk2, src);
                float wx = __shfl(b2x, src), wy = __shfl(b2y, src), wz = __shfl(b2z, src);
                wk48[j] = kw; wxa[j] = wx; wya[j] = wy; wza[j] = wz;
                pwx = wx; pwy = wy; pwz = wz;
                if (blk == 0 && lane == 0) id[s_conf + 1 + j] = (int)(0xFFFFu - (u32)(kw & 0xFFFFull));
            }
        }

        // ---- verify + apply (tentative; exactness check incl. tie-break) ----
        u32 vmask = 0;
        #pragma unroll
        for (int j = 0; j < 8; ++j) {
            if (j < nsub) {
                #pragma unroll
                for (int e = 0; e < 16; ++e) {
                    u64 vk = ((u64)__float_as_uint(md[e]) << 16) | inv[e];
                    if (vk > wk48[j]) vmask |= (1u << j);
                }
                #pragma unroll
                for (int e = 0; e < 16; ++e)
                    md[e] = fminf(md[e], dist3(px[e], py[e], pz[e], wxa[j], wya[j], wza[j]));
            }
        }
        #pragma unroll
        for (int off = 32; off > 0; off >>= 1) vmask |= (u32)__shfl_xor(vmask, off);
        fb_mine = vmask ? (u32)(__ffs(vmask) - 1) : 0xFu;
    }
}

// ---------------- sub_pos / sub_batch outputs ----------------
__global__ void subout_kernel(const float* __restrict__ pos, const int* __restrict__ batch,
                              const int* __restrict__ id, float* __restrict__ sub_pos,
                              int* __restrict__ sub_batch) {
    int m = blockIdx.x * blockDim.x + threadIdx.x;
    if (m >= MCLUS) return;
    int idx = id[m];
    sub_pos[m*3+0] = pos[idx*3+0];
    sub_pos[m*3+1] = pos[idx*3+1];
    sub_pos[m*3+2] = pos[idx*3+2];
    sub_batch[m] = batch[idx];
}

// ---------------- kNN: one wave per query ----------------
// d2 = (|q|^2 - 2*q.p) + |p|^2, all ops correctly-rounded, no FMA (match reference bits).
__global__ __launch_bounds__(64) void knn_kernel(const float* __restrict__ pos,
                                                 const int* __restrict__ id,
                                                 int* __restrict__ nbr) {
    const int q = blockIdx.x;
    const int lane = threadIdx.x;
    const int qi = id[q];
    const float qx = pos[qi*3+0], qy = pos[qi*3+1], qz = pos[qi*3+2];
    const float nq = __fadd_rn(__fadd_rn(__fmul_rn(qx,qx), __fmul_rn(qy,qy)), __fmul_rn(qz,qz));

    float dl[KNN]; int il[KNN];
    #pragma unroll
    for (int t = 0; t < KNN; ++t) { dl[t] = __builtin_inff(); il[t] = 0x7FFFFFFF; }

    for (int j = lane; j < N_PTS; j += 64) {
        float px = pos[j*3+0], py = pos[j*3+1], pz = pos[j*3+2];
        float npj = __fadd_rn(__fadd_rn(__fmul_rn(px,px), __fmul_rn(py,py)), __fmul_rn(pz,pz));
        float dot = __fadd_rn(__fadd_rn(__fmul_rn(qx,px), __fmul_rn(qy,py)), __fmul_rn(qz,pz));
        float d2  = __fadd_rn(__fsub_rn(nq, __fmul_rn(2.0f, dot)), npj);
        if (d2 < dl[KNN-1] || (d2 == dl[KNN-1] && j < il[KNN-1])) {
            dl[KNN-1] = d2; il[KNN-1] = j;
            #pragma unroll
            for (int t = KNN-1; t > 0; --t) {
                float a = dl[t-1], bq = dl[t];
                int   ai = il[t-1], bi = il[t];
                bool sw = (bq < a) || (bq == a && bi < ai);
                dl[t-1] = sw ? bq : a;  dl[t] = sw ? a : bq;
                il[t-1] = sw ? bi : ai; il[t] = sw ? ai : bi;
            }
        }
    }

    __shared__ float sd[64][KNN];
    __shared__ int   si[64][KNN];
    #pragma unroll
    for (int t = 0; t < KNN; ++t) { sd[lane][t] = dl[t]; si[lane][t] = il[t]; }
    __syncthreads();

    // 64-way merge of sorted lists: 16 rounds of wave-min over heads
    int ptr = 0;
    for (int rr = 0; rr < KNN; ++rr) {
        unsigned long long key = ~0ull;
        if (ptr < KNN) {
            unsigned u = __float_as_uint(sd[lane][ptr]);
            unsigned mu = (u >> 31) ? ~u : (u | 0x80000000u);   // order-preserving
            key = ((unsigned long long)mu << 32) | (unsigned)si[lane][ptr];
        }
        unsigned long long m = key;
        #pragma unroll
        for (int off = 32; off > 0; off >>= 1) {
            unsigned long long o = __shfl_xor(m, off);
            if (o < m) m = o;
        }
        if (key == m) ptr++;
        if (lane == 0) nbr[q*KNN + rr] = (int)(m & 0xFFFFFFFFull);
    }
}

// ---------------- BN stats: h = x@W + b, per-channel sum & sumsq ----------------
__global__ __launch_bounds__(256) void stats_kernel(const float* __restrict__ x,
                                                    const float* __restrict__ W,
                                                    const float* __restrict__ b,
                                                    float* __restrict__ psum,
                                                    float* __restrict__ psumsq) {
    __shared__ float xl[64*128];     // 32 KiB
    const int tid = threadIdx.x;
    const int cg = (tid & 63) * 4;   // channel group base
    const int rq = tid >> 6;         // row quarter (0..3)
    float s0=0,s1=0,s2v=0,s3=0, q0=0,q1=0,q2=0,q3=0;
    const float4 bv = *(const float4*)&b[cg];

    for (int t = 0; t < 2; ++t) {
        const size_t row0 = (size_t)blockIdx.x*128 + (size_t)t*64;
        __syncthreads();
        for (int i = tid*4; i < 64*128; i += 1024)
            *(float4*)&xl[i] = *(const float4*)&x[row0*128 + i];
        __syncthreads();

        float acc[16][4];
        #pragma unroll
        for (int rr = 0; rr < 16; ++rr) { acc[rr][0]=bv.x; acc[rr][1]=bv.y; acc[rr][2]=bv.z; acc[rr][3]=bv.w; }

        for (int k4 = 0; k4 < 32; ++k4) {
            float4 w0 = *(const float4*)&W[(k4*4+0)*256 + cg];
            float4 w1 = *(const float4*)&W[(k4*4+1)*256 + cg];
            float4 w2 = *(const float4*)&W[(k4*4+2)*256 + cg];
            float4 w3 = *(const float4*)&W[(k4*4+3)*256 + cg];
            #pragma unroll
            for (int rr = 0; rr < 16; ++rr) {
                float4 xv = *(float4*)&xl[(rq*16+rr)*128 + k4*4];
                acc[rr][0] = fmaf(xv.w,w3.x, fmaf(xv.z,w2.x, fmaf(xv.y,w1.x, fmaf(xv.x,w0.x, acc[rr][0]))));
                acc[rr][1] = fmaf(xv.w,w3.y, fmaf(xv.z,w2.y, fmaf(xv.y,w1.y, fmaf(xv.x,w0.y, acc[rr][1]))));
                acc[rr][2] = fmaf(xv.w,w3.z, fmaf(xv.z,w2.z, fmaf(xv.y,w1.z, fmaf(xv.x,w0.z, acc[rr][2]))));
                acc[rr][3] = fmaf(xv.w,w3.w, fmaf(xv.z,w2.w, fmaf(xv.y,w1.w, fmaf(xv.x,w0.w, acc[rr][3]))));
            }
        }
        #pragma unroll
        for (int rr = 0; rr < 16; ++rr) {
            s0 += acc[rr][0]; q0 = fmaf(acc[rr][0],acc[rr][0],q0);
            s1 += acc[rr][1]; q1 = fmaf(acc[rr][1],acc[rr][1],q1);
            s2v+= acc[rr][2]; q2 = fmaf(acc[rr][2],acc[rr][2],q2);
            s3 += acc[rr][3]; q3 = fmaf(acc[rr][3],acc[rr][3],q3);
        }
    }
    __syncthreads();
    float* red = xl;  // reuse
    red[rq*256 + cg+0] = s0; red[rq*256 + cg+1] = s1; red[rq*256 + cg+2] = s2v; red[rq*256 + cg+3] = s3;
    red[1024 + rq*256 + cg+0] = q0; red[1024 + rq*256 + cg+1] = q1;
    red[1024 + rq*256 + cg+2] = q2; red[1024 + rq*256 + cg+3] = q3;
    __syncthreads();
    if (rq == 0) {
        #pragma unroll
        for (int c = 0; c < 4; ++c) {
            int ch = cg + c;
            float ss = red[ch] + red[256+ch] + red[512+ch] + red[768+ch];
            float qq = red[1024+ch] + red[1280+ch] + red[1536+ch] + red[1792+ch];
            psum  [blockIdx.x*256 + ch] = ss;
            psumsq[blockIdx.x*256 + ch] = qq;
        }
    }
}

__global__ void finalize_kernel(const float* __restrict__ psum, const float* __restrict__ psumsq,
                                const float* __restrict__ gamma, const float* __restrict__ beta,
                                float* __restrict__ scale, float* __restrict__ shift) {
    int c = threadIdx.x;
    float s = 0.f, s2 = 0.f;
    for (int bl = 0; bl < 512; ++bl) { s += psum[bl*256+c]; s2 += psumsq[bl*256+c]; }
    float mu  = s  / 65536.0f;
    float var = s2 / 65536.0f - mu*mu;
    float inv = rsqrtf(var + 1e-5f);
    float sc = gamma[c] * inv;
    scale[c] = sc;
    shift[c] = beta[c] - mu * sc;
}

// ---------------- gather + recompute h rows + pooled BN/ReLU ----------------
__global__ __launch_bounds__(256) void out_kernel(const float* __restrict__ x,
                                                  const float* __restrict__ W,
                                                  const float* __restrict__ b,
                                                  const int* __restrict__ nbr,
                                                  const float* __restrict__ scale,
                                                  const float* __restrict__ shift,
                                                  float* __restrict__ out) {
    __shared__ float xl[16*128];   // 8 KiB
    __shared__ int nb[16];
    const int tid = threadIdx.x;
    const int m = blockIdx.x;
    if (tid < 16) nb[tid] = nbr[m*16 + tid];
    __syncthreads();
    for (int i = tid; i < 16*128; i += 256) {
        int rr = i >> 7, k = i & 127;
        xl[i] = x[(size_t)nb[rr]*128 + k];
    }
    __syncthreads();

    float acc[16];
    const float bias = b[tid];
    #pragma unroll
    for (int rr = 0; rr < 16; ++rr) acc[rr] = bias;

    for (int k4 = 0; k4 < 32; ++k4) {
        float w0 = W[(k4*4+0)*256 + tid];
        float w1 = W[(k4*4+1)*256 + tid];
        float w2 = W[(k4*4+2)*256 + tid];
        float w3 = W[(k4*4+3)*256 + tid];
        #pragma unroll
        for (int rr = 0; rr < 16; ++rr) {
            float4 xv = *(float4*)&xl[rr*128 + k4*4];
            acc[rr] = fmaf(xv.w,w3, fmaf(xv.z,w2, fmaf(xv.y,w1, fmaf(xv.x,w0, acc[rr]))));
        }
    }
    const float sc = scale[tid], sh = shift[tid];
    float v = acc[0];
    #pragma unroll
    for (int rr = 1; rr < 16; ++rr) v = (sc >= 0.f) ? fmaxf(v, acc[rr]) : fminf(v, acc[rr]);
    out[(size_t)m*256 + tid] = fmaxf(fmaf(sc, v, sh), 0.f);
}

// ---------------- launch ----------------
extern "C" void kernel_launch(void* const* d_in, const int* in_sizes, int n_in,
                              void* d_out, int out_size, void* d_ws, size_t ws_size,
                              hipStream_t stream) {
    const float* x     = (const float*)d_in[0];
    const float* pos   = (const float*)d_in[1];
    const int*   batch = (const int*)  d_in[2];
    const float* W     = (const float*)d_in[3];
    const float* b     = (const float*)d_in[4];
    const float* gamma = (const float*)d_in[5];
    const float* beta  = (const float*)d_in[6];

    float* out      = (float*)d_out;
    float* sub_pos  = out + (size_t)MCLUS*C_OUT;
    int*   sub_batch= (int*)(out + (size_t)MCLUS*C_OUT + (size_t)MCLUS*3);

    char* ws = (char*)d_ws;
    int*    id      = (int*)   (ws + WS_ID);
    u64*    slots   = (u64*)   (ws + WS_SLOTS);
    u32*    bbox    = (u32*)   (ws + WS_BBOX);
    int*    cellcnt = (int*)   (ws + WS_CNT);
    int*    cellofs = (int*)   (ws + WS_OFS);
    int*    nbr     = (int*)   (ws + WS_NBR);     // aliases cnt/ofs (dead after scatter)
    float4* pos4    = (float4*)(ws + WS_POS4);    // aliases psum/psumsq (dead after fps)
    float*  psum    = (float*) (ws + WS_PSUM);
    float*  psumsq  = (float*) (ws + WS_PSUMSQ);
    float*  scalep  = (float*) (ws + WS_SCALE);
    float*  shiftp  = (float*) (ws + WS_SHIFT);

    init_kernel<<<1, 1024, 0, stream>>>(id, slots, bbox, cellcnt);
    bbox_kernel<<<64, 256, 0, stream>>>(pos, bbox);
    count_kernel<<<256, 256, 0, stream>>>(pos, bbox, cellcnt);
    scan_kernel<<<1, 1024, 0, stream>>>(cellcnt, cellofs);
    scatter_kernel<<<256, 256, 0, stream>>>(pos, bbox, cellofs, pos4);
    fps_kernel<<<64, 64, 0, stream>>>(pos, pos4, id, slots);
    subout_kernel<<<16, 256, 0, stream>>>(pos, batch, id, sub_pos, sub_batch);
    knn_kernel<<<MCLUS, 64, 0, stream>>>(pos, id, nbr);
    stats_kernel<<<512, 256, 0, stream>>>(x, W, b, psum, psumsq);
    finalize_kernel<<<1, 256, 0, stream>>>(psum, psumsq, gamma, beta, scalep, shiftp);
    out_kernel<<<MCLUS, 256, 0, stream>>>(x, W, b, nbr, scalep, shiftp, out);
}

// Round 13
// 6698.822 us; speedup vs baseline: 1.2334x; 1.2334x over previous
//
#include <hip/hip_runtime.h>
#include <hip/hip_bf16.h>

#define N_PTS 65536
#define MCLUS 4096
#define KNN   16
#define C_IN  128
#define C_OUT 256

typedef unsigned long long u64;
typedef unsigned u32;
typedef unsigned short u16;

// ---------------- workspace layout (bytes) — max 1359936, proven-safe footprint ----
// 0      : id[4096]            int32
// 16384  : slots[2][64][32]    u64   (mailbox; dead after fps -> ALIASED by scale/shift)
// 16384  : scale[256]          f32   (finalize runs after fps)
// 17408  : shift[256]          f32
// 49152  : bbox[6]             u32
// 49216  : cellcnt[32768]      int32 (dead after scan -> ALIASED by nbr u16[4096*16])
// 180288 : cellofs[32768]      int32 (cell END offsets after scatter; live thru knn)
// 311360 : pos4[65536]         float4 (live thru knn; ALIASED by psum/psumsq after)
// 311360 : psum[512*256]       f32   (stats runs after knn)
// 835648 : psumsq[512*256]     f32
#define WS_ID     0
#define WS_SLOTS  16384
#define WS_SCALE  16384
#define WS_SHIFT  17408
#define WS_BBOX   49152
#define WS_CNT    49216
#define WS_NBR    49216
#define WS_OFS    180288
#define WS_POS4   311360
#define WS_PSUM   311360
#define WS_PSUMSQ 835648

// order-preserving float<->u32
__device__ __forceinline__ u32 fkey(float v) {
    u32 u = __float_as_uint(v);
    return (u >> 31) ? ~u : (u | 0x80000000u);
}
__device__ __forceinline__ float funkey(u32 k) {
    u32 u = (k >> 31) ? (k & 0x7FFFFFFFu) : ~k;
    return __uint_as_float(u);
}

// ---------------- init: mailbox, id[0], bbox, cell counts ----------------
__global__ void init_kernel(int* __restrict__ id, u64* __restrict__ slots,
                            u32* __restrict__ bbox, int* __restrict__ cellcnt) {
    int t = threadIdx.x;
    for (int i = t; i < 4096; i += 1024) slots[i] = 0ull;   // tag 0 never used
    for (int i = t; i < 32768; i += 1024) cellcnt[i] = 0;
    if (t < 3)   bbox[t] = 0xFFFFFFFFu;       // mins
    if (t >= 3 && t < 6) bbox[t] = 0u;        // maxes
    if (t == 0) id[0] = 0;
}

// ---------------- bbox: wave-reduced atomic min/max ----------------
__global__ __launch_bounds__(256) void bbox_kernel(const float* __restrict__ pos,
                                                   u32* __restrict__ bbox) {
    int t = blockIdx.x * 256 + threadIdx.x;
    u32 mn0 = 0xFFFFFFFFu, mn1 = 0xFFFFFFFFu, mn2 = 0xFFFFFFFFu;
    u32 mx0 = 0u, mx1 = 0u, mx2 = 0u;
    for (int i = t; i < N_PTS; i += 16384) {
        u32 k0 = fkey(pos[i*3+0]), k1 = fkey(pos[i*3+1]), k2 = fkey(pos[i*3+2]);
        mn0 = min(mn0, k0); mn1 = min(mn1, k1); mn2 = min(mn2, k2);
        mx0 = max(mx0, k0); mx1 = max(mx1, k1); mx2 = max(mx2, k2);
    }
    #pragma unroll
    for (int off = 32; off > 0; off >>= 1) {
        mn0 = min(mn0, (u32)__shfl_xor(mn0, off)); mx0 = max(mx0, (u32)__shfl_xor(mx0, off));
        mn1 = min(mn1, (u32)__shfl_xor(mn1, off)); mx1 = max(mx1, (u32)__shfl_xor(mx1, off));
        mn2 = min(mn2, (u32)__shfl_xor(mn2, off)); mx2 = max(mx2, (u32)__shfl_xor(mx2, off));
    }
    if ((threadIdx.x & 63) == 0) {
        atomicMin(&bbox[0], mn0); atomicMin(&bbox[1], mn1); atomicMin(&bbox[2], mn2);
        atomicMax(&bbox[3], mx0); atomicMax(&bbox[4], mx1); atomicMax(&bbox[5], mx2);
    }
}

// 32x32x32 Morton cell (15-bit), 5 bits per axis interleaved
__device__ __forceinline__ int morton32(int gx, int gy, int gz) {
    int m = 0;
    #pragma unroll
    for (int k = 0; k < 5; ++k)
        m |= (((gx >> k) & 1) << (3*k + 2)) | (((gy >> k) & 1) << (3*k + 1)) | (((gz >> k) & 1) << (3*k));
    return m;
}

__device__ __forceinline__ int cell_of(float x, float y, float z, const u32* bb) {
    float x0 = funkey(bb[0]), y0 = funkey(bb[1]), z0 = funkey(bb[2]);
    float x1 = funkey(bb[3]), y1 = funkey(bb[4]), z1 = funkey(bb[5]);
    float sx = 32.0f / fmaxf(x1 - x0, 1e-20f);
    float sy = 32.0f / fmaxf(y1 - y0, 1e-20f);
    float sz = 32.0f / fmaxf(z1 - z0, 1e-20f);
    int gx = min(max((int)((x - x0) * sx), 0), 31);
    int gy = min(max((int)((y - y0) * sy), 0), 31);
    int gz = min(max((int)((z - z0) * sz), 0), 31);
    return morton32(gx, gy, gz);
}

__global__ __launch_bounds__(256) void count_kernel(const float* __restrict__ pos,
                                                    const u32* __restrict__ bbox,
                                                    int* __restrict__ cellcnt) {
    int i = blockIdx.x * 256 + threadIdx.x;
    atomicAdd(&cellcnt[cell_of(pos[i*3+0], pos[i*3+1], pos[i*3+2], bbox)], 1);
}

// exclusive scan of 32768 cell counts: 1024 threads x 32 cells each
__global__ __launch_bounds__(1024) void scan_kernel(const int* __restrict__ cellcnt,
                                                    int* __restrict__ cellofs) {
    __shared__ int ts[1024];
    int t = threadIdx.x;
    int v[32]; int s = 0;
    #pragma unroll
    for (int i = 0; i < 32; ++i) { v[i] = cellcnt[t*32 + i]; s += v[i]; }
    ts[t] = s; __syncthreads();
    for (int off = 1; off < 1024; off <<= 1) {
        int u = (t >= off) ? ts[t - off] : 0;
        __syncthreads();
        ts[t] += u;
        __syncthreads();
    }
    int pre = (t == 0) ? 0 : ts[t - 1];
    #pragma unroll
    for (int i = 0; i < 32; ++i) { cellofs[t*32 + i] = pre; pre += v[i]; }
}

// after scatter, cellofs[c] = END offset of cell c (start = cellofs[c-1], end[-1]=0)
__global__ __launch_bounds__(256) void scatter_kernel(const float* __restrict__ pos,
                                                      const u32* __restrict__ bbox,
                                                      int* __restrict__ cellofs,
                                                      float4* __restrict__ pos4) {
    int i = blockIdx.x * 256 + threadIdx.x;
    float x = pos[i*3+0], y = pos[i*3+1], z = pos[i*3+2];
    int o = atomicAdd(&cellofs[cell_of(x, y, z, bbox)], 1);
    pos4[o] = make_float4(x, y, z, __int_as_float(i));
}

// exact reference arithmetic: ((dx*dx + dy*dy) + dz*dz), no FMA
__device__ __forceinline__ float dist3(float ax, float ay, float az,
                                       float bx, float by, float bz) {
    float dx = __fsub_rn(ax, bx), dy = __fsub_rn(ay, by), dz = __fsub_rn(az, bz);
    return __fadd_rn(__fadd_rn(__fmul_rn(dx, dx), __fmul_rn(dy, dy)), __fmul_rn(dz, dz));
}

__device__ __forceinline__ u32 wave_max_u32(u32 v) {
    #pragma unroll
    for (int off = 32; off > 0; off >>= 1) {
        u32 o = __shfl_xor(v, off);
        v = o > v ? o : v;
    }
    return v;
}
__device__ __forceinline__ u32 wave_min_u32(u32 v) {
    #pragma unroll
    for (int off = 32; off > 0; off >>= 1) {
        u32 o = __shfl_xor(v, off);
        v = o < v ? o : v;
    }
    return v;
}

// argmax over 48-bit keys (md32<<16 | inv16); returns winning lane.
__device__ __forceinline__ int wave_argmax48(u64 k48) {
    u32 hi = (u32)(k48 >> 16);
    u32 him = wave_max_u32(hi);
    u64 ball = __ballot(hi == him);
    if (__popcll(ball) > 1) {
        u32 a = (hi == him) ? (u32)(k48 & 0xFFFFull) : 0u;
        u32 am = wave_max_u32(a);
        ball = __ballot((hi == him) && (a == am));
    }
    return __ffsll((long long)ball) - 1;
}

// ---------------- FPS: round-8 protocol verbatim (best measured: 6.33 ms) ----------
__global__ __launch_bounds__(64) void fps_kernel(const float* __restrict__ pos,
                                                 const float4* __restrict__ pos4,
                                                 int* __restrict__ id,
                                                 u64* __restrict__ slots) {
    const int lane = threadIdx.x;
    const int blk  = blockIdx.x;
    __shared__ float bku[1024];                      // md snapshot for rollback

    float px[16], py[16], pz[16], md[16];
    u32 inv[16];
    const float c0x = pos[0], c0y = pos[1], c0z = pos[2];
    #pragma unroll
    for (int e = 0; e < 16; ++e) {
        int sp = blk * 1024 + (lane >> 3) * 128 + e * 8 + (lane & 7);
        float4 v = pos4[sp];
        px[e] = v.x; py[e] = v.y; pz[e] = v.z;
        inv[e] = 0xFFFFu - (u32)__float_as_int(v.w);
        md[e] = dist3(px[e], py[e], pz[e], c0x, c0y, c0z);
    }

    int r = 0;              // mailbox round counter (tag = r+1)
    u32 fb_mine = 0xFu;     // first violated substep of previous batch (0xF = clean)

    auto slow_round = [&](int rr, int s) {
        u64 bk = 0; float bx = 0.f, by = 0.f, bz = 0.f;
        #pragma unroll
        for (int e = 0; e < 16; ++e) {
            u64 k = ((u64)__float_as_uint(md[e]) << 16) | inv[e];
            bool bt = k > bk;
            bk = bt ? k : bk; bx = bt ? px[e] : bx; by = bt ? py[e] : by; bz = bt ? pz[e] : bz;
        }
        int src = wave_argmax48(bk);
        float wx = __shfl(bx, src), wy = __shfl(by, src), wz = __shfl(bz, src);
        u64 kb = __shfl(bk, src);

        const u64 tg = (u64)((rr + 1) & 0xFFFF);
        u64* base = &slots[(u32)(rr & 1) * 2048];
        {
            u64 w0 = (kb << 16) | tg;
            u64 w1 = ((u64)__float_as_uint(wx) << 32) | tg;
            u64 w2 = ((u64)__float_as_uint(wy) << 32) | tg;
            u64 w3 = ((u64)__float_as_uint(wz) << 32) | tg;
            u64 wv = (lane == 0) ? w0 : (lane == 1) ? w1 : (lane == 2) ? w2 : w3;
            if (lane < 4)
                __hip_atomic_store(&base[(u32)blk * 32 + (u32)lane], wv,
                                   __ATOMIC_RELAXED, __HIP_MEMORY_SCOPE_AGENT);
        }
        u64* bp = &base[(u32)lane * 32];
        u64 v0, v1, v2, v3;
        for (;;) {
            v0 = __hip_atomic_load(&bp[0], __ATOMIC_RELAXED, __HIP_MEMORY_SCOPE_AGENT);
            v1 = __hip_atomic_load(&bp[1], __ATOMIC_RELAXED, __HIP_MEMORY_SCOPE_AGENT);
            v2 = __hip_atomic_load(&bp[2], __ATOMIC_RELAXED, __HIP_MEMORY_SCOPE_AGENT);
            v3 = __hip_atomic_load(&bp[3], __ATOMIC_RELAXED, __HIP_MEMORY_SCOPE_AGENT);
            u64 bad = ((v0 ^ tg) | (v1 ^ tg) | (v2 ^ tg) | (v3 ^ tg)) & 0xFFFFull;
            if (bad == 0ull) break;
        }
        u64 k2 = v0 >> 16;
        int s2 = wave_argmax48(k2);
        u64 kw = __shfl(k2, s2);
        float cx = __shfl(__uint_as_float((u32)(v1 >> 32)), s2);
        float cy = __shfl(__uint_as_float((u32)(v2 >> 32)), s2);
        float cz = __shfl(__uint_as_float((u32)(v3 >> 32)), s2);
        if (blk == 0 && lane == 0) id[s] = (int)(0xFFFFu - (u32)(kw & 0xFFFFull));
        #pragma unroll
        for (int e = 0; e < 16; ++e)
            md[e] = fminf(md[e], dist3(px[e], py[e], pz[e], cx, cy, cz));
    };

    u64 wk48[8]; float wxa[8], wya[8], wza[8];

    for (int B = 0; B <= 511; ++B) {
        u64 bk = 0; float bx = 0.f, by = 0.f, bz = 0.f;
        #pragma unroll
        for (int e = 0; e < 16; ++e) {
            u64 k = ((u64)__float_as_uint(md[e]) << 16) | inv[e];
            bool bt = k > bk;
            bk = bt ? k : bk; bx = bt ? px[e] : bx; by = bt ? py[e] : by; bz = bt ? pz[e] : bz;
        }
        u64 ks = bk;
        #pragma unroll
        for (int off = 1; off <= 4; off <<= 1) {
            u64 o = __shfl_xor(ks, off);
            if (o > ks) ks = o;
        }
        {
            u64 ball = __ballot(bk == ks);
            int segbase = (lane >> 3) << 3;
            int ssrc = __ffsll((long long)(ball & (0xFFull << segbase))) - 1;
            bx = __shfl(bx, ssrc); by = __shfl(by, ssrc); bz = __shfl(bz, ssrc);
        }

        const u64 tg = (u64)((r + 1) & 0xFFFF);
        u64* base = &slots[(u32)(r & 1) * 2048];
        {
            int c = lane / 3; if (c > 7) c = 7;
            int p = lane - c * 3;
            int srcl = 8 * c;
            u64 kk  = __shfl(ks, srcl);
            float gx = __shfl(bx, srcl), gy = __shfl(by, srcl), gz = __shfl(bz, srcl);
            u32 hi, mid;
            if (p == 0)      { hi = __float_as_uint(gx); mid = (u32)(kk & 0xFFFFull); }
            else if (p == 1) { hi = __float_as_uint(gy); mid = (u32)(kk >> 32) & 0xFFFFu; }
            else             { hi = __float_as_uint(gz); mid = (u32)(kk >> 16) & 0xFFFFu; }
            u64 wd = ((u64)hi << 32) | ((u64)mid << 16) | tg;
            if (lane == 24) wd = ((u64)(fb_mine & 0xFu) << 16) | tg;
            if (lane < 25)
                __hip_atomic_store(&base[(u32)blk * 32 + (u32)lane], wd,
                                   __ATOMIC_RELAXED, __HIP_MEMORY_SCOPE_AGENT);
        }

        u64 w[25]; u32 valid = 0;
        {
            u64* bp = &base[(u32)lane * 32];
            do {
                #pragma unroll
                for (int i = 0; i < 25; ++i)
                    if (!(valid & (1u << i)))
                        w[i] = __hip_atomic_load(&bp[i], __ATOMIC_RELAXED, __HIP_MEMORY_SCOPE_AGENT);
                #pragma unroll
                for (int i = 0; i < 25; ++i)
                    if ((u32)(w[i] & 0xFFFFull) == (u32)tg) valid |= (1u << i);
            } while (valid != 0x1FFFFFFu);
        }
        ++r;

        u32 jstar = wave_min_u32((u32)(w[24] >> 16) & 0xFu);
        if (jstar < 8u) {
            #pragma unroll
            for (int e = 0; e < 16; ++e) md[e] = bku[e * 64 + lane];
            #pragma unroll
            for (int j = 0; j < 8; ++j) {
                if ((u32)j < jstar) {
                    #pragma unroll
                    for (int e = 0; e < 16; ++e)
                        md[e] = fminf(md[e], dist3(px[e], py[e], pz[e], wxa[j], wya[j], wza[j]));
                }
            }
            int sbase = 8 * (B - 1) + 1;
            for (int sub = (int)jstar; sub < 8; ++sub) { slow_round(r, sbase + sub); ++r; }
            fb_mine = 0xFu;
            --B; continue;
        }
        if (B == 511) break;

        float cpx[8], cpy[8], cpz[8], cmdf[8]; u32 cinv[8];
        #pragma unroll
        for (int c = 0; c < 8; ++c) {
            u64 a = w[3 * c], b = w[3 * c + 1], d = w[3 * c + 2];
            cpx[c] = __uint_as_float((u32)(a >> 32));
            cpy[c] = __uint_as_float((u32)(b >> 32));
            cpz[c] = __uint_as_float((u32)(d >> 32));
            cinv[c] = (u32)(a >> 16) & 0xFFFFu;
            u32 mdb = (((u32)(b >> 16) & 0xFFFFu) << 16) | ((u32)(d >> 16) & 0xFFFFu);
            cmdf[c] = __uint_as_float(mdb);
        }

        float pwx = 0.f, pwy = 0.f, pwz = 0.f;
        #pragma unroll
        for (int j = 0; j < 8; ++j) {
            if (j) {
                #pragma unroll
                for (int c = 0; c < 8; ++c)
                    cmdf[c] = fminf(cmdf[c], dist3(cpx[c], cpy[c], cpz[c], pwx, pwy, pwz));
            }
            u64 bk2 = 0; float b2x = 0.f, b2y = 0.f, b2z = 0.f;
            #pragma unroll
            for (int c = 0; c < 8; ++c) {
                u64 k = ((u64)__float_as_uint(cmdf[c]) << 16) | cinv[c];
                bool bt = k > bk2;
                bk2 = bt ? k : bk2; b2x = bt ? cpx[c] : b2x; b2y = bt ? cpy[c] : b2y; b2z = bt ? cpz[c] : b2z;
            }
            int src = wave_argmax48(bk2);
            u64 kw = __shfl(bk2, src);
            float wx = __shfl(b2x, src), wy = __shfl(b2y, src), wz = __shfl(b2z, src);
            wk48[j] = kw; wxa[j] = wx; wya[j] = wy; wza[j] = wz;
            pwx = wx; pwy = wy; pwz = wz;
            if (blk == 0 && lane == 0) id[8 * B + 1 + j] = (int)(0xFFFFu - (u32)(kw & 0xFFFFull));
        }

        #pragma unroll
        for (int e = 0; e < 16; ++e) bku[e * 64 + lane] = md[e];
        u32 vmask = 0;
        #pragma unroll
        for (int j = 0; j < 8; ++j) {
            #pragma unroll
            for (int e = 0; e < 16; ++e) {
                u64 vk = ((u64)__float_as_uint(md[e]) << 16) | inv[e];
                if (vk > wk48[j]) vmask |= (1u << j);
            }
            #pragma unroll
            for (int e = 0; e < 16; ++e)
                md[e] = fminf(md[e], dist3(px[e], py[e], pz[e], wxa[j], wya[j], wza[j]));
        }
        #pragma unroll
        for (int off = 32; off > 0; off >>= 1) vmask |= (u32)__shfl_xor(vmask, off);
        fb_mine = vmask ? (u32)(__ffs(vmask) - 1) : 0xFu;
    }

    for (int s = 4089; s < 4096; ++s) { slow_round(r, s); ++r; }
}

// ---------------- sub_pos / sub_batch outputs ----------------
__global__ void subout_kernel(const float* __restrict__ pos, const int* __restrict__ batch,
                              const int* __restrict__ id, float* __restrict__ sub_pos,
                              int* __restrict__ sub_batch) {
    int m = blockIdx.x * blockDim.x + threadIdx.x;
    if (m >= MCLUS) return;
    int idx = id[m];
    sub_pos[m*3+0] = pos[idx*3+0];
    sub_pos[m*3+1] = pos[idx*3+1];
    sub_pos[m*3+2] = pos[idx*3+2];
    sub_batch[m] = batch[idx];
}

// ---------------- kNN: grid-pruned exact, one wave per query ----------------
// Expanding Chebyshev shells over the 32^3 Morton grid. Cell skipped only if its
// conservative geometric lower bound (0.999x - 1e-3 margins >> ~3e-5 fp error of the
// reference d2 formula) exceeds the current exact wave-wide 16th-best B. Scanned
// points use the bit-exact reference formula + (d2, orig idx) tie-break -> top-16
// SET exact. All wave shuffles execute in UNIFORM control flow (Tpad loop).
__global__ __launch_bounds__(64) void knn_kernel(const float* __restrict__ pos,
                                                 const float4* __restrict__ pos4,
                                                 const int* __restrict__ cellend,
                                                 const u32* __restrict__ bbox,
                                                 const int* __restrict__ id,
                                                 u16* __restrict__ nbr) {
    const int q = blockIdx.x;
    const int lane = threadIdx.x;
    const int qi = id[q];
    const float qx = pos[qi*3+0], qy = pos[qi*3+1], qz = pos[qi*3+2];
    const float nq = __fadd_rn(__fadd_rn(__fmul_rn(qx,qx), __fmul_rn(qy,qy)), __fmul_rn(qz,qz));

    const float x0 = funkey(bbox[0]), y0 = funkey(bbox[1]), z0 = funkey(bbox[2]);
    const float x1 = funkey(bbox[3]), y1 = funkey(bbox[4]), z1 = funkey(bbox[5]);
    const float sx = 32.0f / fmaxf(x1 - x0, 1e-20f);
    const float sy = 32.0f / fmaxf(y1 - y0, 1e-20f);
    const float sz = 32.0f / fmaxf(z1 - z0, 1e-20f);
    const float wx = (x1 - x0) * 0.03125f, wy = (y1 - y0) * 0.03125f, wz = (z1 - z0) * 0.03125f;
    const float wmin = fminf(wx, fminf(wy, wz));
    const int gx = min(max((int)((qx - x0) * sx), 0), 31);
    const int gy = min(max((int)((qy - y0) * sy), 0), 31);
    const int gz = min(max((int)((qz - z0) * sz), 0), 31);

    float dl[KNN]; int il[KNN];
    #pragma unroll
    for (int t = 0; t < KNN; ++t) { dl[t] = __builtin_inff(); il[t] = 0x7FFFFFFF; }

    __shared__ float sd[64][KNN];
    __shared__ int   si[64][KNN];

    // wave-wide exact top-16 merge; returns 16th-best d2 (inf if <16 found).
    auto merge16 = [&](bool writeOut) -> float {
        #pragma unroll
        for (int t = 0; t < KNN; ++t) { sd[lane][t] = dl[t]; si[lane][t] = il[t]; }
        __syncthreads();
        int ptr = 0; u64 m = 0;
        for (int rr = 0; rr < KNN; ++rr) {
            u64 key = ~0ull;
            if (ptr < KNN) {
                u32 u = __float_as_uint(sd[lane][ptr]);
                u32 mu = (u >> 31) ? ~u : (u | 0x80000000u);
                key = ((u64)mu << 32) | (u32)si[lane][ptr];
            }
            m = key;
            #pragma unroll
            for (int off = 32; off > 0; off >>= 1) {
                u64 o = __shfl_xor(m, off);
                if (o < m) m = o;
            }
            if (key == m) ptr++;
            if (writeOut && lane == 0) nbr[q*KNN + rr] = (u16)(m & 0xFFFFull);
        }
        __syncthreads();
        return funkey((u32)(m >> 32));
    };

    float B = __builtin_inff();
    for (int R = 0; R < 32; ++R) {
        const int D = 2*R + 1;
        const int F = D*D;
        const int S = (R == 0) ? 1 : (24*R*R + 2);
        bool any = false;
        for (int bas = 0; bas < S; bas += 64) {
            int i = bas + lane;
            int start = 0, len = 0;
            if (i < S) {
                int dx, dy, dz;
                if (R == 0) { dx = 0; dy = 0; dz = 0; }
                else if (i < 2*F) {
                    dz = (i < F) ? -R : R;
                    int k = (i < F) ? i : i - F;
                    dx = k % D - R; dy = k / D - R;
                } else {
                    int j = i - 2*F, P = 8*R;
                    dz = -R + 1 + j / P;
                    int k = j % P;
                    if (k < D)            { dx = k - R;          dy = -R; }
                    else if (k < 2*D)     { dx = (k - D) - R;    dy =  R; }
                    else {
                        int k3 = k - 2*D;
                        if (k3 < 2*R - 1) { dx = -R; dy = k3 - R + 1; }
                        else              { dx =  R; dy = (k3 - (2*R - 1)) - R + 1; }
                    }
                }
                int cx = gx + dx, cy = gy + dy, cz = gz + dz;
                if ((u32)cx < 32u && (u32)cy < 32u && (u32)cz < 32u) {
                    float lx = (cx == 0)  ? -3.4e38f : x0 + (float)cx * wx;
                    float hx = (cx == 31) ?  3.4e38f : x0 + (float)(cx+1) * wx;
                    float ly = (cy == 0)  ? -3.4e38f : y0 + (float)cy * wy;
                    float hy = (cy == 31) ?  3.4e38f : y0 + (float)(cy+1) * wy;
                    float lz = (cz == 0)  ? -3.4e38f : z0 + (float)cz * wz;
                    float hz = (cz == 31) ?  3.4e38f : z0 + (float)(cz+1) * wz;
                    float ddx = fmaxf(fmaxf(lx - qx, qx - hx), 0.f);
                    float ddy = fmaxf(fmaxf(ly - qy, qy - hy), 0.f);
                    float ddz = fmaxf(fmaxf(lz - qz, qz - hz), 0.f);
                    float md2 = ddx*ddx + ddy*ddy + ddz*ddz;
                    if (md2 * 0.999f - 1e-3f <= B) {
                        int mc = morton32(cx, cy, cz);
                        int end = cellend[mc];
                        start = mc ? cellend[mc-1] : 0;
                        len = end - start;
                    }
                }
            }
            // wave prefix-sum of lens (uniform flow)
            u32 pre = (u32)len;
            #pragma unroll
            for (int off = 1; off < 64; off <<= 1) {
                u32 o = __shfl_up(pre, off);
                if (lane >= off) pre += o;
            }
            u32 T = __shfl(pre, 63);
            pre -= (u32)len;
            if (T == 0) continue;
            any = true;
            // UNIFORM trip count: pad T to multiple of 64; clamp index; predicate insert.
            u32 Tpad = (T + 63u) & ~63u;
            for (u32 t = (u32)lane; t < Tpad; t += 64) {
                bool act = (t < T);
                u32 tt = act ? t : (T - 1u);
                int s = 0;
                #pragma unroll
                for (int step = 32; step > 0; step >>= 1) {
                    int c = s + step;
                    u32 pc = (u32)__shfl(pre, c);
                    if (pc <= tt) s = c;
                }
                u32 p0 = (u32)__shfl(pre, s);
                int st = __shfl(start, s);
                float4 pt = pos4[st + (int)(tt - p0)];
                float npj = __fadd_rn(__fadd_rn(__fmul_rn(pt.x,pt.x), __fmul_rn(pt.y,pt.y)), __fmul_rn(pt.z,pt.z));
                float dot = __fadd_rn(__fadd_rn(__fmul_rn(qx,pt.x), __fmul_rn(qy,pt.y)), __fmul_rn(qz,pt.z));
                float d2  = __fadd_rn(__fsub_rn(nq, __fmul_rn(2.0f, dot)), npj);
                int oi = __float_as_int(pt.w);
                if (act && (d2 < dl[KNN-1] || (d2 == dl[KNN-1] && oi < il[KNN-1]))) {
                    dl[KNN-1] = d2; il[KNN-1] = oi;
                    #pragma unroll
                    for (int t2 = KNN-1; t2 > 0; --t2) {
                        float a = dl[t2-1], bq = dl[t2];
                        int   ai = il[t2-1], bi = il[t2];
                        bool sw = (bq < a) || (bq == a && bi < ai);
                        dl[t2-1] = sw ? bq : a;  dl[t2] = sw ? a : bq;
                        il[t2-1] = sw ? bi : ai; il[t2] = sw ? ai : bi;
                    }
                }
            }
        }
        if (any) B = merge16(false);
        float rw = (float)R * wmin;
        if (rw * rw * 0.999f - 1e-3f > B) break;   // false while B=inf
    }
    merge16(true);
}

// ---------------- BN stats: h = x@W + b, per-channel sum & sumsq ----------------
__global__ __launch_bounds__(256) void stats_kernel(const float* __restrict__ x,
                                                    const float* __restrict__ W,
                                                    const float* __restrict__ b,
                                                    float* __restrict__ psum,
                                                    float* __restrict__ psumsq) {
    __shared__ float xl[64*128];     // 32 KiB
    const int tid = threadIdx.x;
    const int cg = (tid & 63) * 4;   // channel group base
    const int rq = tid >> 6;         // row quarter (0..3)
    float s0=0,s1=0,s2v=0,s3=0, q0=0,q1=0,q2=0,q3=0;
    const float4 bv = *(const float4*)&b[cg];

    for (int t = 0; t < 2; ++t) {
        const size_t row0 = (size_t)blockIdx.x*128 + (size_t)t*64;
        __syncthreads();
        for (int i = tid*4; i < 64*128; i += 1024)
            *(float4*)&xl[i] = *(const float4*)&x[row0*128 + i];
        __syncthreads();

        float acc[16][4];
        #pragma unroll
        for (int rr = 0; rr < 16; ++rr) { acc[rr][0]=bv.x; acc[rr][1]=bv.y; acc[rr][2]=bv.z; acc[rr][3]=bv.w; }

        for (int k4 = 0; k4 < 32; ++k4) {
            float4 w0 = *(const float4*)&W[(k4*4+0)*256 + cg];
            float4 w1 = *(const float4*)&W[(k4*4+1)*256 + cg];
            float4 w2 = *(const float4*)&W[(k4*4+2)*256 + cg];
            float4 w3 = *(const float4*)&W[(k4*4+3)*256 + cg];
            #pragma unroll
            for (int rr = 0; rr < 16; ++rr) {
                float4 xv = *(float4*)&xl[(rq*16+rr)*128 + k4*4];
                acc[rr][0] = fmaf(xv.w,w3.x, fmaf(xv.z,w2.x, fmaf(xv.y,w1.x, fmaf(xv.x,w0.x, acc[rr][0]))));
                acc[rr][1] = fmaf(xv.w,w3.y, fmaf(xv.z,w2.y, fmaf(xv.y,w1.y, fmaf(xv.x,w0.y, acc[rr][1]))));
                acc[rr][2] = fmaf(xv.w,w3.z, fmaf(xv.z,w2.z, fmaf(xv.y,w1.z, fmaf(xv.x,w0.z, acc[rr][2]))));
                acc[rr][3] = fmaf(xv.w,w3.w, fmaf(xv.z,w2.w, fmaf(xv.y,w1.w, fmaf(xv.x,w0.w, acc[rr][3]))));
            }
        }
        #pragma unroll
        for (int rr = 0; rr < 16; ++rr) {
            s0 += acc[rr][0]; q0 = fmaf(acc[rr][0],acc[rr][0],q0);
            s1 += acc[rr][1]; q1 = fmaf(acc[rr][1],acc[rr][1],q1);
            s2v+= acc[rr][2]; q2 = fmaf(acc[rr][2],acc[rr][2],q2);
            s3 += acc[rr][3]; q3 = fmaf(acc[rr][3],acc[rr][3],q3);
        }
    }
    __syncthreads();
    float* red = xl;  // reuse
    red[rq*256 + cg+0] = s0; red[rq*256 + cg+1] = s1; red[rq*256 + cg+2] = s2v; red[rq*256 + cg+3] = s3;
    red[1024 + rq*256 + cg+0] = q0; red[1024 + rq*256 + cg+1] = q1;
    red[1024 + rq*256 + cg+2] = q2; red[1024 + rq*256 + cg+3] = q3;
    __syncthreads();
    if (rq == 0) {
        #pragma unroll
        for (int c = 0; c < 4; ++c) {
            int ch = cg + c;
            float ss = red[ch] + red[256+ch] + red[512+ch] + red[768+ch];
            float qq = red[1024+ch] + red[1280+ch] + red[1536+ch] + red[1792+ch];
            psum  [blockIdx.x*256 + ch] = ss;
            psumsq[blockIdx.x*256 + ch] = qq;
        }
    }
}

__global__ void finalize_kernel(const float* __restrict__ psum, const float* __restrict__ psumsq,
                                const float* __restrict__ gamma, const float* __restrict__ beta,
                                float* __restrict__ scale, float* __restrict__ shift) {
    int c = threadIdx.x;
    float s = 0.f, s2 = 0.f;
    for (int bl = 0; bl < 512; ++bl) { s += psum[bl*256+c]; s2 += psumsq[bl*256+c]; }
    float mu  = s  / 65536.0f;
    float var = s2 / 65536.0f - mu*mu;
    float inv = rsqrtf(var + 1e-5f);
    float sc = gamma[c] * inv;
    scale[c] = sc;
    shift[c] = beta[c] - mu * sc;
}

// ---------------- gather + recompute h rows + pooled BN/ReLU ----------------
__global__ __launch_bounds__(256) void out_kernel(const float* __restrict__ x,
                                                  const float* __restrict__ W,
                                                  const float* __restrict__ b,
                                                  const u16* __restrict__ nbr,
                                                  const float* __restrict__ scale,
                                                  const float* __restrict__ shift,
                                                  float* __restrict__ out) {
    __shared__ float xl[16*128];   // 8 KiB
    __shared__ int nb[16];
    const int tid = threadIdx.x;
    const int m = blockIdx.x;
    if (tid < 16) nb[tid] = (int)nbr[m*16 + tid];
    __syncthreads();
    for (int i = tid; i < 16*128; i += 256) {
        int rr = i >> 7, k = i & 127;
        xl[i] = x[(size_t)nb[rr]*128 + k];
    }
    __syncthreads();

    float acc[16];
    const float bias = b[tid];
    #pragma unroll
    for (int rr = 0; rr < 16; ++rr) acc[rr] = bias;

    for (int k4 = 0; k4 < 32; ++k4) {
        float w0 = W[(k4*4+0)*256 + tid];
        float w1 = W[(k4*4+1)*256 + tid];
        float w2 = W[(k4*4+2)*256 + tid];
        float w3 = W[(k4*4+3)*256 + tid];
        #pragma unroll
        for (int rr = 0; rr < 16; ++rr) {
            float4 xv = *(float4*)&xl[rr*128 + k4*4];
            acc[rr] = fmaf(xv.w,w3, fmaf(xv.z,w2, fmaf(xv.y,w1, fmaf(xv.x,w0, acc[rr]))));
        }
    }
    const float sc = scale[tid], sh = shift[tid];
    float v = acc[0];
    #pragma unroll
    for (int rr = 1; rr < 16; ++rr) v = (sc >= 0.f) ? fmaxf(v, acc[rr]) : fminf(v, acc[rr]);
    out[(size_t)m*256 + tid] = fmaxf(fmaf(sc, v, sh), 0.f);
}

// ---------------- launch ----------------
extern "C" void kernel_launch(void* const* d_in, const int* in_sizes, int n_in,
                              void* d_out, int out_size, void* d_ws, size_t ws_size,
                              hipStream_t stream) {
    const float* x     = (const float*)d_in[0];
    const float* pos   = (const float*)d_in[1];
    const int*   batch = (const int*)  d_in[2];
    const float* W     = (const float*)d_in[3];
    const float* b     = (const float*)d_in[4];
    const float* gamma = (const float*)d_in[5];
    const float* beta  = (const float*)d_in[6];

    float* out      = (float*)d_out;
    float* sub_pos  = out + (size_t)MCLUS*C_OUT;
    int*   sub_batch= (int*)(out + (size_t)MCLUS*C_OUT + (size_t)MCLUS*3);

    char* ws = (char*)d_ws;
    int*    id      = (int*)   (ws + WS_ID);
    u64*    slots   = (u64*)   (ws + WS_SLOTS);
    float*  scalep  = (float*) (ws + WS_SCALE);   // aliases slots (dead after fps)
    float*  shiftp  = (float*) (ws + WS_SHIFT);
    u32*    bbox    = (u32*)   (ws + WS_BBOX);
    int*    cellcnt = (int*)   (ws + WS_CNT);
    u16*    nbr     = (u16*)   (ws + WS_NBR);     // aliases cellcnt (dead after scan)
    int*    cellofs = (int*)   (ws + WS_OFS);     // live thru knn
    float4* pos4    = (float4*)(ws + WS_POS4);    // live thru knn; psum/psumsq alias after
    float*  psum    = (float*) (ws + WS_PSUM);
    float*  psumsq  = (float*) (ws + WS_PSUMSQ);

    init_kernel<<<1, 1024, 0, stream>>>(id, slots, bbox, cellcnt);
    bbox_kernel<<<64, 256, 0, stream>>>(pos, bbox);
    count_kernel<<<256, 256, 0, stream>>>(pos, bbox, cellcnt);
    scan_kernel<<<1, 1024, 0, stream>>>(cellcnt, cellofs);
    scatter_kernel<<<256, 256, 0, stream>>>(pos, bbox, cellofs, pos4);
    fps_kernel<<<64, 64, 0, stream>>>(pos, pos4, id, slots);
    subout_kernel<<<16, 256, 0, stream>>>(pos, batch, id, sub_pos, sub_batch);
    knn_kernel<<<MCLUS, 64, 0, stream>>>(pos, pos4, cellofs, bbox, id, nbr);
    stats_kernel<<<512, 256, 0, stream>>>(x, W, b, psum, psumsq);
    finalize_kernel<<<1, 256, 0, stream>>>(psum, psumsq, gamma, beta, scalep, shiftp);
    out_kernel<<<MCLUS, 256, 0, stream>>>(x, W, b, nbr, scalep, shiftp, out);
}